// Round 2
// baseline (493.112 us; speedup 1.0000x reference)
//
#include <hip/hip_runtime.h>
#include <cstddef>
#include <cstdint>

// Problem constants
#define BZd   128
#define Td    32
#define Dd    768
#define DFFd  3072
#define Ed    8
#define NBEAM 256                 // BZ * BEAMS
#define ROWS_TOT 8192             // NBEAM * T
#define OUT_ELEMS 6291456         // 256*32*768
#define MAXTILES 72               // max sum ceil(cnt_e*32/128) = 70, padded

typedef unsigned short u16;
typedef __attribute__((ext_vector_type(4))) unsigned short ushort4v;
typedef __attribute__((ext_vector_type(8))) short frag_ab;   // 8 x bf16 (4 VGPRs)
typedef __attribute__((ext_vector_type(4))) float floatx4;

__device__ __forceinline__ u16 f2bf(float f) {
  unsigned int u = __builtin_bit_cast(unsigned int, f);
  u += 0x7FFFu + ((u >> 16) & 1u);     // round-to-nearest-even; inputs are finite
  return (u16)(u >> 16);
}

// ---------------------------------------------------------------------------
// Routing: x_avg = mean_T(x); logits = x_avg @ Wg; softmax; top-2.
// One block per batch. Writes beam_scores + expert_route into d_out tail,
// int sel[] into workspace.
// ---------------------------------------------------------------------------
__global__ __launch_bounds__(256) void route_kernel(
    const float* __restrict__ x, const float* __restrict__ Wg,
    float* __restrict__ out, int* __restrict__ sel) {
  int b = blockIdx.x;
  int t = threadIdx.x;
  __shared__ float red[256][8];
  float la[8];
#pragma unroll
  for (int e = 0; e < 8; e++) la[e] = 0.f;
  for (int d = t; d < Dd; d += 256) {
    const float* xp = x + (size_t)b * Td * Dd + d;
    float xa = 0.f;
#pragma unroll
    for (int tt = 0; tt < Td; tt++) xa += xp[(size_t)tt * Dd];
    xa *= (1.0f / 32.0f);
#pragma unroll
    for (int e = 0; e < 8; e++) la[e] += xa * Wg[d * 8 + e];
  }
#pragma unroll
  for (int e = 0; e < 8; e++) red[t][e] = la[e];
  __syncthreads();
  for (int s = 128; s > 0; s >>= 1) {
    if (t < s) {
#pragma unroll
      for (int e = 0; e < 8; e++) red[t][e] += red[t + s][e];
    }
    __syncthreads();
  }
  if (t == 0) {
    float lg[8];
#pragma unroll
    for (int e = 0; e < 8; e++) lg[e] = red[0][e];
    float mx = lg[0];
#pragma unroll
    for (int e = 1; e < 8; e++) mx = fmaxf(mx, lg[e]);
    float p[8];
    float sum = 0.f;
#pragma unroll
    for (int e = 0; e < 8; e++) { p[e] = __expf(lg[e] - mx); sum += p[e]; }
    float inv = 1.0f / sum;
#pragma unroll
    for (int e = 0; e < 8; e++) p[e] *= inv;
    // top-2, ties -> lower index (strict > for replacement)
    int i0 = 0; float v0 = p[0];
#pragma unroll
    for (int e = 1; e < 8; e++) if (p[e] > v0) { v0 = p[e]; i0 = e; }
    int i1 = -1; float v1 = -1.0f;
#pragma unroll
    for (int e = 0; e < 8; e++) if (e != i0 && p[e] > v1) { v1 = p[e]; i1 = e; }
    float* bs = out + OUT_ELEMS;          // beam_scores (256)
    float* er = out + OUT_ELEMS + NBEAM;  // expert_route (256)
    bs[2 * b] = v0; bs[2 * b + 1] = v1;
    er[2 * b] = (float)i0; er[2 * b + 1] = (float)i1;
    sel[2 * b] = i0; sel[2 * b + 1] = i1;
  }
}

// ---------------------------------------------------------------------------
// Bucket: group beams by expert; emit perm[] and padded tile metadata.
// tiles[i] = (expert, global_ordered_row0, valid_rows, 0); e=-1 pads.
// ---------------------------------------------------------------------------
__global__ __launch_bounds__(256) void bucket_kernel(
    const int* __restrict__ sel, int* __restrict__ perm, int4* __restrict__ tiles) {
  __shared__ int ssel[NBEAM];
  __shared__ int scnt[8];
  __shared__ int soff[8];
  __shared__ int scur[8];
  __shared__ int sperm[NBEAM];
  int t = threadIdx.x;
  ssel[t] = sel[t];
  __syncthreads();
  if (t == 0) {
    for (int e = 0; e < 8; e++) scnt[e] = 0;
    for (int n = 0; n < NBEAM; n++) scnt[ssel[n]]++;
    int o = 0;
    for (int e = 0; e < 8; e++) { soff[e] = o; scur[e] = o; o += scnt[e]; }
    for (int n = 0; n < NBEAM; n++) { int e = ssel[n]; sperm[scur[e]++] = n; }
    int tt = 0;
    for (int e = 0; e < 8; e++) {
      int nr = scnt[e] * 32;           // token rows for this expert
      int base = soff[e] * 32;         // global ordered row start
      for (int r0 = 0; r0 < nr; r0 += 128) {
        tiles[tt] = make_int4(e, base + r0, min(128, nr - r0), 0);
        tt++;
      }
    }
    for (; tt < MAXTILES; tt++) tiles[tt] = make_int4(-1, 0, 0, 0);
  }
  __syncthreads();
  perm[t] = sperm[t];
}

// ---------------------------------------------------------------------------
// GEMM1: h[r, f] = gelu( X[r,:] @ W1[e][:, f0+f] + b1[e][f0+f] ), bf16 out.
// Tile: 128 rows x 128 cols, BK=32, mfma_f32_16x16x32_bf16.
// LDS layout: As[m][k], Bs[n][k] (transposed), row stride 40 bf16 (80B) ->
// b128 frag reads land 2-way on banks (free, m136).
// ---------------------------------------------------------------------------
__global__ __launch_bounds__(256) void gemm1_kernel(
    const float* __restrict__ x, const float* __restrict__ W1,
    const float* __restrict__ b1, const int* __restrict__ perm,
    const int4* __restrict__ tiles, u16* __restrict__ h, int f0, int FC) {
  int4 meta = tiles[blockIdx.y];
  int e = meta.x;
  if (e < 0) return;
  int grow0 = meta.y, nrows = meta.z;
  int bx = blockIdx.x;

  __shared__ __align__(16) u16 As[128 * 40];
  __shared__ __align__(16) u16 Bs[128 * 40];
  __shared__ int sbatch[4];

  int t = threadIdx.x;
  if (t < 4) {
    int idx = (grow0 >> 5) + t;
    sbatch[t] = perm[idx < NBEAM ? idx : NBEAM - 1] >> 1;  // batch = beam>>1
  }
  __syncthreads();

  int wave = t >> 6, lane = t & 63;
  int wm = wave & 1, wn = wave >> 1;
  int lrow = lane & 15, lquad = lane >> 4;

  // A staging map: thread covers rows (t>>3)+32*i, k-float4 (t&7)*4
  int a_k4 = (t & 7) * 4;
  int a_m0 = t >> 3;          // also the token index within the beam
  // B staging map: thread covers col n=t&127, k-halves (t>>7)*16..+16
  int b_n = t & 127;
  int b_k0 = (t >> 7) * 16;
  const float* Bp = W1 + (size_t)e * Dd * DFFd + (size_t)(f0 + bx * 128 + b_n);

  floatx4 acc[4][4];
#pragma unroll
  for (int mi = 0; mi < 4; mi++)
#pragma unroll
    for (int ni = 0; ni < 4; ni++) acc[mi][ni] = (floatx4){0.f, 0.f, 0.f, 0.f};

  for (int kt = 0; kt < Dd; kt += 32) {
    // stage A (x rows, fp32 -> bf16)
#pragma unroll
    for (int i = 0; i < 4; i++) {
      int m = a_m0 + 32 * i;
      float4 v = make_float4(0.f, 0.f, 0.f, 0.f);
      if (m < nrows)
        v = *(const float4*)(x + ((size_t)sbatch[i] * Td + a_m0) * Dd + kt + a_k4);
      ushort4v pv;
      pv.x = f2bf(v.x); pv.y = f2bf(v.y); pv.z = f2bf(v.z); pv.w = f2bf(v.w);
      *(ushort4v*)(&As[m * 40 + a_k4]) = pv;
    }
    // stage B (W1 tile, transposed into Bs[n][k])
    const float* BpK = Bp + (size_t)kt * DFFd;
#pragma unroll
    for (int jj = 0; jj < 4; jj++) {
      int kl = b_k0 + jj * 4;
      ushort4v pv;
      pv.x = f2bf(BpK[(size_t)(kl + 0) * DFFd]);
      pv.y = f2bf(BpK[(size_t)(kl + 1) * DFFd]);
      pv.z = f2bf(BpK[(size_t)(kl + 2) * DFFd]);
      pv.w = f2bf(BpK[(size_t)(kl + 3) * DFFd]);
      *(ushort4v*)(&Bs[b_n * 40 + kl]) = pv;
    }
    __syncthreads();

    frag_ab af[4], bf[4];
    const u16* Ab = As + (wm * 64 + lrow) * 40 + lquad * 8;
    const u16* Bb = Bs + (wn * 64 + lrow) * 40 + lquad * 8;
#pragma unroll
    for (int mi = 0; mi < 4; mi++) af[mi] = *(const frag_ab*)(Ab + mi * 16 * 40);
#pragma unroll
    for (int ni = 0; ni < 4; ni++) bf[ni] = *(const frag_ab*)(Bb + ni * 16 * 40);
#pragma unroll
    for (int mi = 0; mi < 4; mi++)
#pragma unroll
      for (int ni = 0; ni < 4; ni++)
        acc[mi][ni] = __builtin_amdgcn_mfma_f32_16x16x32_bf16(af[mi], bf[ni], acc[mi][ni], 0, 0, 0);
    __syncthreads();
  }

  // epilogue: bias + exact gelu -> bf16 h
  int f_base = bx * 128;
#pragma unroll
  for (int mi = 0; mi < 4; mi++) {
    int row0 = wm * 64 + mi * 16 + lquad * 4;
#pragma unroll
    for (int ni = 0; ni < 4; ni++) {
      int col = wn * 64 + ni * 16 + lrow;
      float bias = b1[(size_t)e * DFFd + f0 + f_base + col];
#pragma unroll
      for (int r = 0; r < 4; r++) {
        int row = row0 + r;
        if (row < nrows) {
          float vv = acc[mi][ni][r] + bias;
          float g = 0.5f * vv * (1.0f + erff(vv * 0.70710678118654752f));
          h[(size_t)(grow0 + row) * FC + f_base + col] = f2bf(g);
        }
      }
    }
  }
}

// ---------------------------------------------------------------------------
// GEMM2: out[beam, tok, d] (+)= h[r,:] @ W2[e][f0:, d] (+ b2[e][d] on chunk 0)
// ---------------------------------------------------------------------------
__global__ __launch_bounds__(256) void gemm2_kernel(
    const u16* __restrict__ h, const float* __restrict__ W2,
    const float* __restrict__ b2, const int* __restrict__ perm,
    const int4* __restrict__ tiles, float* __restrict__ out,
    int f0, int FC, int first) {
  int4 meta = tiles[blockIdx.y];
  int e = meta.x;
  if (e < 0) return;
  int grow0 = meta.y, nrows = meta.z;
  int bx = blockIdx.x;

  __shared__ __align__(16) u16 As[128 * 40];
  __shared__ __align__(16) u16 Bs[128 * 40];
  __shared__ int sbeam[4];

  int t = threadIdx.x;
  if (t < 4) {
    int idx = (grow0 >> 5) + t;
    sbeam[t] = perm[idx < NBEAM ? idx : NBEAM - 1];
  }
  __syncthreads();

  int wave = t >> 6, lane = t & 63;
  int wm = wave & 1, wn = wave >> 1;
  int lrow = lane & 15, lquad = lane >> 4;

  // A staging: thread t covers row m=t>>1, bf16 elements [(t&1)*16, (t&1)*16+16)
  // via TWO uint4 copies (uint4 = 8 bf16). Round-1 bug: a single uint4 left
  // k in [8,16)+[24,32) as stale LDS -> absmax 5.08. Fixed here.
  int a_m = t >> 1;
  int a_kq = (t & 1) * 16;
  // B staging: same map as gemm1, W2 stride = Dd
  int b_n = t & 127;
  int b_k0 = (t >> 7) * 16;
  const float* Bp = W2 + (size_t)e * DFFd * Dd + (size_t)(bx * 128 + b_n);

  floatx4 acc[4][4];
#pragma unroll
  for (int mi = 0; mi < 4; mi++)
#pragma unroll
    for (int ni = 0; ni < 4; ni++) acc[mi][ni] = (floatx4){0.f, 0.f, 0.f, 0.f};

  for (int kt = 0; kt < FC; kt += 32) {
    // stage A: bf16 h rows, 2 x 16B vector copy (full 32-element coverage)
    uint4 v0 = make_uint4(0u, 0u, 0u, 0u);
    uint4 v1 = make_uint4(0u, 0u, 0u, 0u);
    if (a_m < nrows) {
      const uint4* p = (const uint4*)(h + (size_t)(grow0 + a_m) * FC + kt + a_kq);
      v0 = p[0];
      v1 = p[1];
    }
    *(uint4*)(&As[a_m * 40 + a_kq]) = v0;
    *(uint4*)(&As[a_m * 40 + a_kq + 8]) = v1;
    // stage B: W2 tile transposed into Bs[n][k]
    const float* BpK = Bp + (size_t)(f0 + kt) * Dd;
#pragma unroll
    for (int jj = 0; jj < 4; jj++) {
      int kl = b_k0 + jj * 4;
      ushort4v pv;
      pv.x = f2bf(BpK[(size_t)(kl + 0) * Dd]);
      pv.y = f2bf(BpK[(size_t)(kl + 1) * Dd]);
      pv.z = f2bf(BpK[(size_t)(kl + 2) * Dd]);
      pv.w = f2bf(BpK[(size_t)(kl + 3) * Dd]);
      *(ushort4v*)(&Bs[b_n * 40 + kl]) = pv;
    }
    __syncthreads();

    frag_ab af[4], bf[4];
    const u16* Ab = As + (wm * 64 + lrow) * 40 + lquad * 8;
    const u16* Bb = Bs + (wn * 64 + lrow) * 40 + lquad * 8;
#pragma unroll
    for (int mi = 0; mi < 4; mi++) af[mi] = *(const frag_ab*)(Ab + mi * 16 * 40);
#pragma unroll
    for (int ni = 0; ni < 4; ni++) bf[ni] = *(const frag_ab*)(Bb + ni * 16 * 40);
#pragma unroll
    for (int mi = 0; mi < 4; mi++)
#pragma unroll
      for (int ni = 0; ni < 4; ni++)
        acc[mi][ni] = __builtin_amdgcn_mfma_f32_16x16x32_bf16(af[mi], bf[ni], acc[mi][ni], 0, 0, 0);
    __syncthreads();
  }

  int d_base = bx * 128;
#pragma unroll
  for (int mi = 0; mi < 4; mi++) {
    int row0 = wm * 64 + mi * 16 + lquad * 4;
#pragma unroll
    for (int ni = 0; ni < 4; ni++) {
      int col = wn * 64 + ni * 16 + lrow;
      int dg = d_base + col;
      float bias = b2[(size_t)e * Dd + dg];
#pragma unroll
      for (int r = 0; r < 4; r++) {
        int row = row0 + r;
        if (row < nrows) {
          int beam = sbeam[row >> 5];
          size_t o = ((size_t)beam * Td + (row & 31)) * Dd + dg;
          if (first) out[o] = acc[mi][ni][r] + bias;
          else out[o] += acc[mi][ni][r];
        }
      }
    }
  }
}

// ---------------------------------------------------------------------------
extern "C" void kernel_launch(void* const* d_in, const int* in_sizes, int n_in,
                              void* d_out, int out_size, void* d_ws, size_t ws_size,
                              hipStream_t stream) {
  const float* x  = (const float*)d_in[0];
  // d_in[1] attention_mask: ignored (reference rebuilds a ones mask)
  const float* Wg = (const float*)d_in[2];
  const float* W1 = (const float*)d_in[3];
  const float* b1 = (const float*)d_in[4];
  const float* W2 = (const float*)d_in[5];
  const float* b2 = (const float*)d_in[6];
  float* out = (float*)d_out;

  char* ws = (char*)d_ws;
  int*  sel   = (int*)ws;                  // 256 ints
  int*  perm  = sel + NBEAM;               // 256 ints
  int4* tiles = (int4*)(ws + 4096);        // 72 int4
  u16*  h     = (u16*)(ws + 65536);

  // Choose DFF chunk size by available workspace (constant across calls).
  size_t avail = ws_size > 65536 ? ws_size - 65536 : 0;
  int FC = 384;
  if      (avail >= (size_t)ROWS_TOT * 3072 * 2) FC = 3072;
  else if (avail >= (size_t)ROWS_TOT * 1536 * 2) FC = 1536;
  else if (avail >= (size_t)ROWS_TOT * 768  * 2) FC = 768;
  int NC = DFFd / FC;

  route_kernel<<<BZd, 256, 0, stream>>>(x, Wg, out, sel);
  bucket_kernel<<<1, 256, 0, stream>>>(sel, perm, tiles);
  for (int c = 0; c < NC; c++) {
    gemm1_kernel<<<dim3(FC / 128, MAXTILES), 256, 0, stream>>>(
        x, W1, b1, perm, tiles, h, c * FC, FC);
    gemm2_kernel<<<dim3(Dd / 128, MAXTILES), 256, 0, stream>>>(
        h, W2, b2, perm, tiles, out, c * FC, FC, c == 0 ? 1 : 0);
  }
}

// Round 3
// 460.299 us; speedup vs baseline: 1.0713x; 1.0713x over previous
//
#include <hip/hip_runtime.h>
#include <cstddef>
#include <cstdint>

#define BZd   128
#define Td    32
#define Dd    768
#define DFFd  3072
#define Ed    8
#define NBEAM 256
#define ROWS_TOT 8192
#define OUT_ELEMS 6291456
#define MAXTILES 72

typedef unsigned short u16;
typedef __attribute__((ext_vector_type(4))) unsigned short ushort4v;
typedef __attribute__((ext_vector_type(8))) short frag_ab;
typedef __attribute__((ext_vector_type(4))) float floatx4;

__device__ __forceinline__ u16 f2bf(float f) {
  unsigned int u = __builtin_bit_cast(unsigned int, f);
  u += 0x7FFFu + ((u >> 16) & 1u);
  return (u16)(u >> 16);
}

// async global->LDS, 16B per lane; lds base must be wave-uniform.
__device__ __forceinline__ void async_copy16(u16* lds, const u16* g) {
  __builtin_amdgcn_global_load_lds(
      (const __attribute__((address_space(1))) void*)g,
      (__attribute__((address_space(3))) void*)lds, 16, 0, 0);
}

// ---------------------------------------------------------------------------
// Routing (unchanged from round 2 — verified)
// ---------------------------------------------------------------------------
__global__ __launch_bounds__(256) void route_kernel(
    const float* __restrict__ x, const float* __restrict__ Wg,
    float* __restrict__ out, int* __restrict__ sel) {
  int b = blockIdx.x;
  int t = threadIdx.x;
  __shared__ float red[256][8];
  float la[8];
#pragma unroll
  for (int e = 0; e < 8; e++) la[e] = 0.f;
  for (int d = t; d < Dd; d += 256) {
    const float* xp = x + (size_t)b * Td * Dd + d;
    float xa = 0.f;
#pragma unroll
    for (int tt = 0; tt < Td; tt++) xa += xp[(size_t)tt * Dd];
    xa *= (1.0f / 32.0f);
#pragma unroll
    for (int e = 0; e < 8; e++) la[e] += xa * Wg[d * 8 + e];
  }
#pragma unroll
  for (int e = 0; e < 8; e++) red[t][e] = la[e];
  __syncthreads();
  for (int s = 128; s > 0; s >>= 1) {
    if (t < s) {
#pragma unroll
      for (int e = 0; e < 8; e++) red[t][e] += red[t + s][e];
    }
    __syncthreads();
  }
  if (t == 0) {
    float lg[8];
#pragma unroll
    for (int e = 0; e < 8; e++) lg[e] = red[0][e];
    float mx = lg[0];
#pragma unroll
    for (int e = 1; e < 8; e++) mx = fmaxf(mx, lg[e]);
    float p[8];
    float sum = 0.f;
#pragma unroll
    for (int e = 0; e < 8; e++) { p[e] = __expf(lg[e] - mx); sum += p[e]; }
    float inv = 1.0f / sum;
#pragma unroll
    for (int e = 0; e < 8; e++) p[e] *= inv;
    int i0 = 0; float v0 = p[0];
#pragma unroll
    for (int e = 1; e < 8; e++) if (p[e] > v0) { v0 = p[e]; i0 = e; }
    int i1 = -1; float v1 = -1.0f;
#pragma unroll
    for (int e = 0; e < 8; e++) if (e != i0 && p[e] > v1) { v1 = p[e]; i1 = e; }
    float* bs = out + OUT_ELEMS;
    float* er = out + OUT_ELEMS + NBEAM;
    bs[2 * b] = v0; bs[2 * b + 1] = v1;
    er[2 * b] = (float)i0; er[2 * b + 1] = (float)i1;
    sel[2 * b] = i0; sel[2 * b + 1] = i1;
  }
}

// ---------------------------------------------------------------------------
// Bucket (unchanged)
// ---------------------------------------------------------------------------
__global__ __launch_bounds__(256) void bucket_kernel(
    const int* __restrict__ sel, int* __restrict__ perm, int4* __restrict__ tiles) {
  __shared__ int ssel[NBEAM];
  __shared__ int scnt[8];
  __shared__ int soff[8];
  __shared__ int scur[8];
  __shared__ int sperm[NBEAM];
  int t = threadIdx.x;
  ssel[t] = sel[t];
  __syncthreads();
  if (t == 0) {
    for (int e = 0; e < 8; e++) scnt[e] = 0;
    for (int n = 0; n < NBEAM; n++) scnt[ssel[n]]++;
    int o = 0;
    for (int e = 0; e < 8; e++) { soff[e] = o; scur[e] = o; o += scnt[e]; }
    for (int n = 0; n < NBEAM; n++) { int e = ssel[n]; sperm[scur[e]++] = n; }
    int tt = 0;
    for (int e = 0; e < 8; e++) {
      int nr = scnt[e] * 32;
      int base = soff[e] * 32;
      for (int r0 = 0; r0 < nr; r0 += 128) {
        tiles[tt] = make_int4(e, base + r0, min(128, nr - r0), 0);
        tt++;
      }
    }
    for (; tt < MAXTILES; tt++) tiles[tt] = make_int4(-1, 0, 0, 0);
  }
  __syncthreads();
  perm[t] = sperm[t];
}

// ---------------------------------------------------------------------------
// init_out: out[beam][tok][d] = b2[sel[beam]][d]  (gemm2 atomically adds on top)
// ---------------------------------------------------------------------------
__global__ __launch_bounds__(256) void init_out_kernel(
    const float* __restrict__ b2, const int* __restrict__ sel,
    float* __restrict__ out) {
  int n = blockIdx.x;
  int t = threadIdx.x;
  int e = sel[n];
  __shared__ float sb2[Dd];
  for (int d = t; d < Dd; d += 256) sb2[d] = b2[(size_t)e * Dd + d];
  __syncthreads();
  float* op = out + (size_t)n * Td * Dd;
#pragma unroll
  for (int k = 0; k < 24; k++) {
    int flat = (k * 256 + t) * 4;
    int d = flat % Dd;
    float4 v = make_float4(sb2[d], sb2[d + 1], sb2[d + 2], sb2[d + 3]);
    *(float4*)(op + flat) = v;
  }
}

// ---------------------------------------------------------------------------
// convert_x: fp32 -> bf16
// ---------------------------------------------------------------------------
__global__ __launch_bounds__(256) void convert_x_kernel(
    const float* __restrict__ x, u16* __restrict__ xbf) {
  size_t i = ((size_t)blockIdx.x * 256 + threadIdx.x) * 4;
  float4 v = *(const float4*)(x + i);
  ushort4v pv = {f2bf(v.x), f2bf(v.y), f2bf(v.z), f2bf(v.w)};
  *(ushort4v*)(xbf + i) = pv;
}

// ---------------------------------------------------------------------------
// Tiled transpose + fp32->bf16:
//   out[e*estr_out + (c0+cc)*ld_out + (r0+r)] = bf16(in[e*estr_in + (row0+r0+r)*ld_in + col0+c0+cc])
// 64x64 tiles, LDS stride 65 (u16) -> write-phase column gathers land 2-way.
// ---------------------------------------------------------------------------
__global__ __launch_bounds__(256) void transpose_bf16_kernel(
    const float* __restrict__ in, u16* __restrict__ out, int row0, int col0,
    int ld_in, size_t estr_in, int ld_out, size_t estr_out) {
  __shared__ u16 tile[64][65];
  int e = blockIdx.z;
  int r0 = blockIdx.x * 64, c0 = blockIdx.y * 64;
  int t = threadIdx.x;
  int rr = t >> 4, cc4 = (t & 15) * 4;
  const float* ip = in + (size_t)e * estr_in + (size_t)(row0 + r0) * ld_in + col0 + c0;
#pragma unroll
  for (int i = 0; i < 4; i++) {
    int r = rr + 16 * i;
    float4 v = *(const float4*)(ip + (size_t)r * ld_in + cc4);
    tile[r][cc4 + 0] = f2bf(v.x);
    tile[r][cc4 + 1] = f2bf(v.y);
    tile[r][cc4 + 2] = f2bf(v.z);
    tile[r][cc4 + 3] = f2bf(v.w);
  }
  __syncthreads();
  int ccw = t >> 4, r4 = (t & 15) * 4;
  u16* op = out + (size_t)e * estr_out + (size_t)c0 * ld_out + r0;
#pragma unroll
  for (int i = 0; i < 4; i++) {
    int cc = ccw + 16 * i;
    ushort4v pv = {tile[r4 + 0][cc], tile[r4 + 1][cc], tile[r4 + 2][cc], tile[r4 + 3][cc]};
    *(ushort4v*)(op + (size_t)cc * ld_out + r4) = pv;
  }
}

// ---------------------------------------------------------------------------
// GEMM1: h[r][f] = gelu(X @ W1T^T + b1), m97 structure.
// A,B staged unpadded [128][32] via global_load_lds w=16; XOR k-swizzle
// (kslot ^ (row>>1)&3) at both stage & read -> 2-way banks.
// ---------------------------------------------------------------------------
__global__ __launch_bounds__(256) void gemm1_kernel(
    const u16* __restrict__ xbf, const u16* __restrict__ w1t,
    const float* __restrict__ b1, const int* __restrict__ perm,
    const int4* __restrict__ tiles, u16* __restrict__ h, int f0, int FC) {
  int4 meta = tiles[blockIdx.y];
  int e = meta.x;
  if (e < 0) return;
  int grow0 = meta.y, nrows = meta.z;
  int bx = blockIdx.x;

  __shared__ __align__(16) u16 As[128 * 32];
  __shared__ __align__(16) u16 Bs[128 * 32];

  int t = threadIdx.x;
  int l = t & 63, w = t >> 6;
  int wm = w & 1, wn = w >> 1;
  int lrow = l & 15, lquad = l >> 4;

  const u16* ag[2]; const u16* bg[2];
  u16* al[2]; u16* bl[2];
#pragma unroll
  for (int j = 0; j < 2; j++) {
    int s = (w * 2 + j) * 64 + l;
    int m = s >> 2;
    int koff = ((s & 3) ^ ((m >> 1) & 3)) * 8;
    int bidx = (grow0 >> 5) + (m >> 5);
    bidx = bidx < NBEAM ? bidx : NBEAM - 1;
    int batch = perm[bidx] >> 1;
    ag[j] = xbf + ((size_t)batch * Td + (m & 31)) * Dd + koff;
    bg[j] = w1t + ((size_t)e * FC + bx * 128 + m) * Dd + koff;
    al[j] = As + (size_t)(w * 2 + j) * 512;
    bl[j] = Bs + (size_t)(w * 2 + j) * 512;
  }

  int aoff[4], boff[4];
#pragma unroll
  for (int i = 0; i < 4; i++) {
    int ra = wm * 64 + i * 16 + lrow;
    aoff[i] = ra * 32 + (lquad ^ ((ra >> 1) & 3)) * 8;
    int rb = wn * 64 + i * 16 + lrow;
    boff[i] = rb * 32 + (lquad ^ ((rb >> 1) & 3)) * 8;
  }

  floatx4 acc[4][4];
#pragma unroll
  for (int mi = 0; mi < 4; mi++)
#pragma unroll
    for (int ni = 0; ni < 4; ni++) acc[mi][ni] = (floatx4){0.f, 0.f, 0.f, 0.f};

  for (int kt = 0; kt < Dd; kt += 32) {
#pragma unroll
    for (int j = 0; j < 2; j++) {
      async_copy16(al[j], ag[j]);
      async_copy16(bl[j], bg[j]);
      ag[j] += 32; bg[j] += 32;
    }
    __syncthreads();
    frag_ab af[4], bf[4];
#pragma unroll
    for (int mi = 0; mi < 4; mi++) af[mi] = *(const frag_ab*)(As + aoff[mi]);
#pragma unroll
    for (int ni = 0; ni < 4; ni++) bf[ni] = *(const frag_ab*)(Bs + boff[ni]);
#pragma unroll
    for (int mi = 0; mi < 4; mi++)
#pragma unroll
      for (int ni = 0; ni < 4; ni++)
        acc[mi][ni] = __builtin_amdgcn_mfma_f32_16x16x32_bf16(af[mi], bf[ni], acc[mi][ni], 0, 0, 0);
    __syncthreads();
  }

  int f_base = bx * 128;
#pragma unroll
  for (int mi = 0; mi < 4; mi++) {
    int row0 = wm * 64 + mi * 16 + lquad * 4;
#pragma unroll
    for (int ni = 0; ni < 4; ni++) {
      int col = wn * 64 + ni * 16 + lrow;
      float bias = b1[(size_t)e * DFFd + f0 + f_base + col];
#pragma unroll
      for (int r = 0; r < 4; r++) {
        int row = row0 + r;
        if (row < nrows) {
          float vv = acc[mi][ni][r] + bias;
          float g = 0.5f * vv * (1.0f + erff(vv * 0.70710678118654752f));
          h[(size_t)(grow0 + row) * FC + f_base + col] = f2bf(g);
        }
      }
    }
  }
}

// ---------------------------------------------------------------------------
// GEMM2: out[beam][tok][d] += h @ W2T^T   (bias was pre-written by init_out)
// split-K over blockIdx.z; fp32 atomicAdd epilogue.
// ---------------------------------------------------------------------------
__global__ __launch_bounds__(256) void gemm2_kernel(
    const u16* __restrict__ h, const u16* __restrict__ w2t,
    const int* __restrict__ perm, const int4* __restrict__ tiles,
    float* __restrict__ out, int FC, int KD) {
  int4 meta = tiles[blockIdx.y];
  int e = meta.x;
  if (e < 0) return;
  int grow0 = meta.y, nrows = meta.z;
  int bx = blockIdx.x;
  int kz = blockIdx.z * KD;

  __shared__ __align__(16) u16 As[128 * 32];
  __shared__ __align__(16) u16 Bs[128 * 32];
  __shared__ int sbeam[4];

  int t = threadIdx.x;
  if (t < 4) {
    int idx = (grow0 >> 5) + t;
    sbeam[t] = perm[idx < NBEAM ? idx : NBEAM - 1];
  }
  int l = t & 63, w = t >> 6;
  int wm = w & 1, wn = w >> 1;
  int lrow = l & 15, lquad = l >> 4;

  const u16* ag[2]; const u16* bg[2];
  u16* al[2]; u16* bl[2];
#pragma unroll
  for (int j = 0; j < 2; j++) {
    int s = (w * 2 + j) * 64 + l;
    int m = s >> 2;
    int koff = ((s & 3) ^ ((m >> 1) & 3)) * 8;
    int arow = grow0 + m;
    arow = arow < ROWS_TOT ? arow : ROWS_TOT - 1;
    ag[j] = h + (size_t)arow * FC + kz + koff;
    bg[j] = w2t + ((size_t)e * Dd + bx * 128 + m) * FC + kz + koff;
    al[j] = As + (size_t)(w * 2 + j) * 512;
    bl[j] = Bs + (size_t)(w * 2 + j) * 512;
  }

  int aoff[4], boff[4];
#pragma unroll
  for (int i = 0; i < 4; i++) {
    int ra = wm * 64 + i * 16 + lrow;
    aoff[i] = ra * 32 + (lquad ^ ((ra >> 1) & 3)) * 8;
    int rb = wn * 64 + i * 16 + lrow;
    boff[i] = rb * 32 + (lquad ^ ((rb >> 1) & 3)) * 8;
  }

  floatx4 acc[4][4];
#pragma unroll
  for (int mi = 0; mi < 4; mi++)
#pragma unroll
    for (int ni = 0; ni < 4; ni++) acc[mi][ni] = (floatx4){0.f, 0.f, 0.f, 0.f};

  for (int kt = 0; kt < KD; kt += 32) {
#pragma unroll
    for (int j = 0; j < 2; j++) {
      async_copy16(al[j], ag[j]);
      async_copy16(bl[j], bg[j]);
      ag[j] += 32; bg[j] += 32;
    }
    __syncthreads();
    frag_ab af[4], bf[4];
#pragma unroll
    for (int mi = 0; mi < 4; mi++) af[mi] = *(const frag_ab*)(As + aoff[mi]);
#pragma unroll
    for (int ni = 0; ni < 4; ni++) bf[ni] = *(const frag_ab*)(Bs + boff[ni]);
#pragma unroll
    for (int mi = 0; mi < 4; mi++)
#pragma unroll
      for (int ni = 0; ni < 4; ni++)
        acc[mi][ni] = __builtin_amdgcn_mfma_f32_16x16x32_bf16(af[mi], bf[ni], acc[mi][ni], 0, 0, 0);
    __syncthreads();
  }

#pragma unroll
  for (int mi = 0; mi < 4; mi++) {
    int row0 = wm * 64 + mi * 16 + lquad * 4;
#pragma unroll
    for (int ni = 0; ni < 4; ni++) {
      int col = wn * 64 + ni * 16 + lrow;
      int dg = bx * 128 + col;
#pragma unroll
      for (int r = 0; r < 4; r++) {
        int row = row0 + r;
        if (row < nrows) {
          int beam = sbeam[row >> 5];
          atomicAdd(out + ((size_t)beam * Td + (row & 31)) * Dd + dg, acc[mi][ni][r]);
        }
      }
    }
  }
}

// ---------------------------------------------------------------------------
extern "C" void kernel_launch(void* const* d_in, const int* in_sizes, int n_in,
                              void* d_out, int out_size, void* d_ws, size_t ws_size,
                              hipStream_t stream) {
  const float* x  = (const float*)d_in[0];
  const float* Wg = (const float*)d_in[2];
  const float* W1 = (const float*)d_in[3];
  const float* b1 = (const float*)d_in[4];
  const float* W2 = (const float*)d_in[5];
  const float* b2 = (const float*)d_in[6];
  float* out = (float*)d_out;

  char* ws = (char*)d_ws;
  int*  sel   = (int*)ws;
  int*  perm  = sel + NBEAM;
  int4* tiles = (int4*)(ws + 4096);

  // workspace: [meta 64K][xbf 12.6M][W1T chunk][W2T chunk][h chunk]
  const size_t xbf_off = 65536;
  const size_t xbf_bytes = (size_t)BZd * Td * Dd * 2;         // 12,582,912
  int FC = 384;
  if      (xbf_off + xbf_bytes + (size_t)40960 * 3072 <= ws_size) FC = 3072;
  else if (xbf_off + xbf_bytes + (size_t)40960 * 1536 <= ws_size) FC = 1536;
  else if (xbf_off + xbf_bytes + (size_t)40960 * 768  <= ws_size) FC = 768;
  int NC = DFFd / FC;
  int KSPLIT = (FC >= 1536) ? 2 : 1;
  int KD = FC / KSPLIT;

  u16* xbf = (u16*)(ws + xbf_off);
  u16* w1t = (u16*)(ws + xbf_off + xbf_bytes);
  u16* w2t = w1t + (size_t)Ed * FC * Dd;
  u16* h   = w2t + (size_t)Ed * Dd * FC;

  route_kernel<<<BZd, 256, 0, stream>>>(x, Wg, out, sel);
  bucket_kernel<<<1, 256, 0, stream>>>(sel, perm, tiles);
  init_out_kernel<<<NBEAM, 256, 0, stream>>>(b2, sel, out);
  convert_x_kernel<<<(BZd * Td * Dd) / 1024, 256, 0, stream>>>(x, xbf);

  for (int c = 0; c < NC; c++) {
    // W1T[e][f][d] = W1[e][d][c*FC + f]
    transpose_bf16_kernel<<<dim3(Dd / 64, FC / 64, Ed), 256, 0, stream>>>(
        W1, w1t, 0, c * FC, DFFd, (size_t)Dd * DFFd, Dd, (size_t)FC * Dd);
    // W2T[e][d][f] = W2[e][c*FC + f][d]
    transpose_bf16_kernel<<<dim3(FC / 64, Dd / 64, Ed), 256, 0, stream>>>(
        W2, w2t, c * FC, 0, Dd, (size_t)DFFd * Dd, FC, (size_t)Dd * FC);
    gemm1_kernel<<<dim3(FC / 128, MAXTILES), 256, 0, stream>>>(
        xbf, w1t, b1, perm, tiles, h, c * FC, FC);
    gemm2_kernel<<<dim3(Dd / 128, MAXTILES, KSPLIT), 256, 0, stream>>>(
        h, w2t, perm, tiles, out, FC, KD);
  }
}

// Round 4
// 393.066 us; speedup vs baseline: 1.2545x; 1.1710x over previous
//
#include <hip/hip_runtime.h>
#include <cstddef>
#include <cstdint>

#define BZd   128
#define Td    32
#define Dd    768
#define DFFd  3072
#define Ed    8
#define NBEAM 256
#define ROWS_TOT 8192
#define OUT_ELEMS 6291456
#define MAXTILES 72

typedef unsigned short u16;
typedef __attribute__((ext_vector_type(4))) unsigned short ushort4v;
typedef __attribute__((ext_vector_type(8))) short frag_ab;
typedef __attribute__((ext_vector_type(4))) float floatx4;

__device__ __forceinline__ u16 f2bf(float f) {
  unsigned int u = __builtin_bit_cast(unsigned int, f);
  u += 0x7FFFu + ((u >> 16) & 1u);
  return (u16)(u >> 16);
}

__device__ __forceinline__ void async_copy16(u16* lds, const u16* g) {
  __builtin_amdgcn_global_load_lds(
      (const __attribute__((address_space(1))) void*)g,
      (__attribute__((address_space(3))) void*)lds, 16, 0, 0);
}

// fast gelu (tanh form via sigmoid): max abs err ~3e-4, << 0.14 threshold
__device__ __forceinline__ float gelu_fast(float x) {
  float z = 1.5957691216f * (x + 0.044715f * x * x * x);
  return x / (1.0f + __expf(-z));
}

// ---------------------------------------------------------------------------
// Routing (byte-identical math to round 2/3 — near-tie softmax, don't perturb)
// ---------------------------------------------------------------------------
__global__ __launch_bounds__(256) void route_kernel(
    const float* __restrict__ x, const float* __restrict__ Wg,
    float* __restrict__ out, int* __restrict__ sel) {
  int b = blockIdx.x;
  int t = threadIdx.x;
  __shared__ float red[256][8];
  float la[8];
#pragma unroll
  for (int e = 0; e < 8; e++) la[e] = 0.f;
  for (int d = t; d < Dd; d += 256) {
    const float* xp = x + (size_t)b * Td * Dd + d;
    float xa = 0.f;
#pragma unroll
    for (int tt = 0; tt < Td; tt++) xa += xp[(size_t)tt * Dd];
    xa *= (1.0f / 32.0f);
#pragma unroll
    for (int e = 0; e < 8; e++) la[e] += xa * Wg[d * 8 + e];
  }
#pragma unroll
  for (int e = 0; e < 8; e++) red[t][e] = la[e];
  __syncthreads();
  for (int s = 128; s > 0; s >>= 1) {
    if (t < s) {
#pragma unroll
      for (int e = 0; e < 8; e++) red[t][e] += red[t + s][e];
    }
    __syncthreads();
  }
  if (t == 0) {
    float lg[8];
#pragma unroll
    for (int e = 0; e < 8; e++) lg[e] = red[0][e];
    float mx = lg[0];
#pragma unroll
    for (int e = 1; e < 8; e++) mx = fmaxf(mx, lg[e]);
    float p[8];
    float sum = 0.f;
#pragma unroll
    for (int e = 0; e < 8; e++) { p[e] = __expf(lg[e] - mx); sum += p[e]; }
    float inv = 1.0f / sum;
#pragma unroll
    for (int e = 0; e < 8; e++) p[e] *= inv;
    int i0 = 0; float v0 = p[0];
#pragma unroll
    for (int e = 1; e < 8; e++) if (p[e] > v0) { v0 = p[e]; i0 = e; }
    int i1 = -1; float v1 = -1.0f;
#pragma unroll
    for (int e = 0; e < 8; e++) if (e != i0 && p[e] > v1) { v1 = p[e]; i1 = e; }
    float* bs = out + OUT_ELEMS;
    float* er = out + OUT_ELEMS + NBEAM;
    bs[2 * b] = v0; bs[2 * b + 1] = v1;
    er[2 * b] = (float)i0; er[2 * b + 1] = (float)i1;
    sel[2 * b] = i0; sel[2 * b + 1] = i1;
  }
}

// ---------------------------------------------------------------------------
// Bucket (unchanged)
// ---------------------------------------------------------------------------
__global__ __launch_bounds__(256) void bucket_kernel(
    const int* __restrict__ sel, int* __restrict__ perm, int4* __restrict__ tiles) {
  __shared__ int ssel[NBEAM];
  __shared__ int scnt[8];
  __shared__ int soff[8];
  __shared__ int scur[8];
  __shared__ int sperm[NBEAM];
  int t = threadIdx.x;
  ssel[t] = sel[t];
  __syncthreads();
  if (t == 0) {
    for (int e = 0; e < 8; e++) scnt[e] = 0;
    for (int n = 0; n < NBEAM; n++) scnt[ssel[n]]++;
    int o = 0;
    for (int e = 0; e < 8; e++) { soff[e] = o; scur[e] = o; o += scnt[e]; }
    for (int n = 0; n < NBEAM; n++) { int e = ssel[n]; sperm[scur[e]++] = n; }
    int tt = 0;
    for (int e = 0; e < 8; e++) {
      int nr = scnt[e] * 32;
      int base = soff[e] * 32;
      for (int r0 = 0; r0 < nr; r0 += 128) {
        tiles[tt] = make_int4(e, base + r0, min(128, nr - r0), 0);
        tt++;
      }
    }
    for (; tt < MAXTILES; tt++) tiles[tt] = make_int4(-1, 0, 0, 0);
  }
  __syncthreads();
  perm[t] = sperm[t];
}

// ---------------------------------------------------------------------------
// convert_x: fp32 -> bf16
// ---------------------------------------------------------------------------
__global__ __launch_bounds__(256) void convert_x_kernel(
    const float* __restrict__ x, u16* __restrict__ xbf) {
  size_t i = ((size_t)blockIdx.x * 256 + threadIdx.x) * 4;
  float4 v = *(const float4*)(x + i);
  ushort4v pv = {f2bf(v.x), f2bf(v.y), f2bf(v.z), f2bf(v.w)};
  *(ushort4v*)(xbf + i) = pv;
}

// ---------------------------------------------------------------------------
// Tiled transpose + fp32->bf16 (unchanged from round 3)
// ---------------------------------------------------------------------------
__global__ __launch_bounds__(256) void transpose_bf16_kernel(
    const float* __restrict__ in, u16* __restrict__ out, int row0, int col0,
    int ld_in, size_t estr_in, int ld_out, size_t estr_out) {
  __shared__ u16 tile[64][65];
  int e = blockIdx.z;
  int r0 = blockIdx.x * 64, c0 = blockIdx.y * 64;
  int t = threadIdx.x;
  int rr = t >> 4, cc4 = (t & 15) * 4;
  const float* ip = in + (size_t)e * estr_in + (size_t)(row0 + r0) * ld_in + col0 + c0;
#pragma unroll
  for (int i = 0; i < 4; i++) {
    int r = rr + 16 * i;
    float4 v = *(const float4*)(ip + (size_t)r * ld_in + cc4);
    tile[r][cc4 + 0] = f2bf(v.x);
    tile[r][cc4 + 1] = f2bf(v.y);
    tile[r][cc4 + 2] = f2bf(v.z);
    tile[r][cc4 + 3] = f2bf(v.w);
  }
  __syncthreads();
  int ccw = t >> 4, r4 = (t & 15) * 4;
  u16* op = out + (size_t)e * estr_out + (size_t)c0 * ld_out + r0;
#pragma unroll
  for (int i = 0; i < 4; i++) {
    int cc = ccw + 16 * i;
    ushort4v pv = {tile[r4 + 0][cc], tile[r4 + 1][cc], tile[r4 + 2][cc], tile[r4 + 3][cc]};
    *(ushort4v*)(op + (size_t)cc * ld_out + r4) = pv;
  }
}

// ---------------------------------------------------------------------------
// GEMM1: h = gelu(X @ W1T^T + b1). BK=64, unpadded [128][64] LDS tiles via
// global_load_lds w=16; XOR chunk-swizzle (c ^ (row>>1)&7) -> 2-way banks.
// 32 MFMA per barrier-pair.
// ---------------------------------------------------------------------------
__global__ __launch_bounds__(256) void gemm1_kernel(
    const u16* __restrict__ xbf, const u16* __restrict__ w1t,
    const float* __restrict__ b1, const int* __restrict__ perm,
    const int4* __restrict__ tiles, u16* __restrict__ h, int f0, int FC) {
  int4 meta = tiles[blockIdx.y];
  int e = meta.x;
  if (e < 0) return;
  int grow0 = meta.y, nrows = meta.z;
  int bx = blockIdx.x;

  __shared__ __align__(16) u16 As[128 * 64];
  __shared__ __align__(16) u16 Bs[128 * 64];

  int t = threadIdx.x;
  int l = t & 63, w = t >> 6;
  int wm = w & 1, wn = w >> 1;
  int lrow = l & 15, lquad = l >> 4;

  const u16* ag[4]; const u16* bg[4];
  u16* al[4]; u16* bl[4];
#pragma unroll
  for (int j = 0; j < 4; j++) {
    int s = j * 256 + t;
    int m = s >> 3;
    int koff = (((s & 7) ^ ((m >> 1) & 7))) * 8;
    int bidx = (grow0 >> 5) + (m >> 5);
    bidx = bidx < NBEAM ? bidx : NBEAM - 1;
    int batch = perm[bidx] >> 1;
    ag[j] = xbf + ((size_t)batch * Td + (m & 31)) * Dd + koff;
    bg[j] = w1t + ((size_t)e * FC + bx * 128 + m) * Dd + koff;
    al[j] = As + j * 2048 + w * 512;
    bl[j] = Bs + j * 2048 + w * 512;
  }

  int aoff[2][4], boff[2][4];
#pragma unroll
  for (int hh = 0; hh < 2; hh++)
#pragma unroll
    for (int i = 0; i < 4; i++) {
      int ra = wm * 64 + i * 16 + lrow;
      aoff[hh][i] = ra * 64 + (((lquad + hh * 4) ^ ((ra >> 1) & 7)) * 8);
      int rb = wn * 64 + i * 16 + lrow;
      boff[hh][i] = rb * 64 + (((lquad + hh * 4) ^ ((rb >> 1) & 7)) * 8);
    }

  floatx4 acc[4][4];
#pragma unroll
  for (int mi = 0; mi < 4; mi++)
#pragma unroll
    for (int ni = 0; ni < 4; ni++) acc[mi][ni] = (floatx4){0.f, 0.f, 0.f, 0.f};

  for (int kt = 0; kt < Dd; kt += 64) {
#pragma unroll
    for (int j = 0; j < 4; j++) {
      async_copy16(al[j], ag[j]);
      async_copy16(bl[j], bg[j]);
      ag[j] += 64; bg[j] += 64;
    }
    __syncthreads();
#pragma unroll
    for (int hh = 0; hh < 2; hh++) {
      frag_ab af[4], bf[4];
#pragma unroll
      for (int mi = 0; mi < 4; mi++) af[mi] = *(const frag_ab*)(As + aoff[hh][mi]);
#pragma unroll
      for (int ni = 0; ni < 4; ni++) bf[ni] = *(const frag_ab*)(Bs + boff[hh][ni]);
#pragma unroll
      for (int mi = 0; mi < 4; mi++)
#pragma unroll
        for (int ni = 0; ni < 4; ni++)
          acc[mi][ni] = __builtin_amdgcn_mfma_f32_16x16x32_bf16(af[mi], bf[ni], acc[mi][ni], 0, 0, 0);
    }
    __syncthreads();
  }

  int f_base = bx * 128;
#pragma unroll
  for (int mi = 0; mi < 4; mi++) {
    int row0 = wm * 64 + mi * 16 + lquad * 4;
#pragma unroll
    for (int ni = 0; ni < 4; ni++) {
      int col = wn * 64 + ni * 16 + lrow;
      float bias = b1[(size_t)e * DFFd + f0 + f_base + col];
#pragma unroll
      for (int r = 0; r < 4; r++) {
        int row = row0 + r;
        if (row < nrows) {
          float vv = acc[mi][ni][r] + bias;
          h[(size_t)(grow0 + row) * FC + f_base + col] = f2bf(gelu_fast(vv));
        }
      }
    }
  }
}

// ---------------------------------------------------------------------------
// GEMM2: out[beam][tok][d] = h @ W2T^T + b2. BK=64, no split-K, no atomics —
// each (m-tile, bx) block exclusively owns its output region.
// ---------------------------------------------------------------------------
__global__ __launch_bounds__(256) void gemm2_kernel(
    const u16* __restrict__ h, const u16* __restrict__ w2t,
    const float* __restrict__ b2, const int* __restrict__ perm,
    const int4* __restrict__ tiles, float* __restrict__ out,
    int FC, int first) {
  int4 meta = tiles[blockIdx.y];
  int e = meta.x;
  if (e < 0) return;
  int grow0 = meta.y, nrows = meta.z;
  int bx = blockIdx.x;

  __shared__ __align__(16) u16 As[128 * 64];
  __shared__ __align__(16) u16 Bs[128 * 64];
  __shared__ int sbeam[4];

  int t = threadIdx.x;
  if (t < 4) {
    int idx = (grow0 >> 5) + t;
    sbeam[t] = perm[idx < NBEAM ? idx : NBEAM - 1];
  }
  int l = t & 63, w = t >> 6;
  int wm = w & 1, wn = w >> 1;
  int lrow = l & 15, lquad = l >> 4;

  const u16* ag[4]; const u16* bg[4];
  u16* al[4]; u16* bl[4];
#pragma unroll
  for (int j = 0; j < 4; j++) {
    int s = j * 256 + t;
    int m = s >> 3;
    int koff = (((s & 7) ^ ((m >> 1) & 7))) * 8;
    int arow = grow0 + m;
    arow = arow < ROWS_TOT ? arow : ROWS_TOT - 1;
    ag[j] = h + (size_t)arow * FC + koff;
    bg[j] = w2t + ((size_t)e * Dd + bx * 128 + m) * FC + koff;
    al[j] = As + j * 2048 + w * 512;
    bl[j] = Bs + j * 2048 + w * 512;
  }

  int aoff[2][4], boff[2][4];
#pragma unroll
  for (int hh = 0; hh < 2; hh++)
#pragma unroll
    for (int i = 0; i < 4; i++) {
      int ra = wm * 64 + i * 16 + lrow;
      aoff[hh][i] = ra * 64 + (((lquad + hh * 4) ^ ((ra >> 1) & 7)) * 8);
      int rb = wn * 64 + i * 16 + lrow;
      boff[hh][i] = rb * 64 + (((lquad + hh * 4) ^ ((rb >> 1) & 7)) * 8);
    }

  floatx4 acc[4][4];
#pragma unroll
  for (int mi = 0; mi < 4; mi++)
#pragma unroll
    for (int ni = 0; ni < 4; ni++) acc[mi][ni] = (floatx4){0.f, 0.f, 0.f, 0.f};

  for (int kt = 0; kt < FC; kt += 64) {
#pragma unroll
    for (int j = 0; j < 4; j++) {
      async_copy16(al[j], ag[j]);
      async_copy16(bl[j], bg[j]);
      ag[j] += 64; bg[j] += 64;
    }
    __syncthreads();
#pragma unroll
    for (int hh = 0; hh < 2; hh++) {
      frag_ab af[4], bf[4];
#pragma unroll
      for (int mi = 0; mi < 4; mi++) af[mi] = *(const frag_ab*)(As + aoff[hh][mi]);
#pragma unroll
      for (int ni = 0; ni < 4; ni++) bf[ni] = *(const frag_ab*)(Bs + boff[hh][ni]);
#pragma unroll
      for (int mi = 0; mi < 4; mi++)
#pragma unroll
        for (int ni = 0; ni < 4; ni++)
          acc[mi][ni] = __builtin_amdgcn_mfma_f32_16x16x32_bf16(af[mi], bf[ni], acc[mi][ni], 0, 0, 0);
    }
    __syncthreads();
  }

#pragma unroll
  for (int mi = 0; mi < 4; mi++) {
    int row0 = wm * 64 + mi * 16 + lquad * 4;
#pragma unroll
    for (int ni = 0; ni < 4; ni++) {
      int col = wn * 64 + ni * 16 + lrow;
      int dg = bx * 128 + col;
      float bias = b2[(size_t)e * Dd + dg];
#pragma unroll
      for (int r = 0; r < 4; r++) {
        int row = row0 + r;
        if (row < nrows) {
          int beam = sbeam[row >> 5];
          size_t o = ((size_t)beam * Td + (row & 31)) * Dd + dg;
          if (first) out[o] = acc[mi][ni][r] + bias;
          else out[o] += acc[mi][ni][r];
        }
      }
    }
  }
}

// ---------------------------------------------------------------------------
extern "C" void kernel_launch(void* const* d_in, const int* in_sizes, int n_in,
                              void* d_out, int out_size, void* d_ws, size_t ws_size,
                              hipStream_t stream) {
  const float* x  = (const float*)d_in[0];
  const float* Wg = (const float*)d_in[2];
  const float* W1 = (const float*)d_in[3];
  const float* b1 = (const float*)d_in[4];
  const float* W2 = (const float*)d_in[5];
  const float* b2 = (const float*)d_in[6];
  float* out = (float*)d_out;

  char* ws = (char*)d_ws;
  int*  sel   = (int*)ws;
  int*  perm  = sel + NBEAM;
  int4* tiles = (int4*)(ws + 4096);

  const size_t xbf_off = 65536;
  const size_t xbf_bytes = (size_t)BZd * Td * Dd * 2;
  int FC = 384;
  if      (xbf_off + xbf_bytes + (size_t)40960 * 3072 <= ws_size) FC = 3072;
  else if (xbf_off + xbf_bytes + (size_t)40960 * 1536 <= ws_size) FC = 1536;
  else if (xbf_off + xbf_bytes + (size_t)40960 * 768  <= ws_size) FC = 768;
  int NC = DFFd / FC;

  u16* xbf = (u16*)(ws + xbf_off);
  u16* w1t = (u16*)(ws + xbf_off + xbf_bytes);
  u16* w2t = w1t + (size_t)Ed * FC * Dd;
  u16* h   = w2t + (size_t)Ed * Dd * FC;

  route_kernel<<<BZd, 256, 0, stream>>>(x, Wg, out, sel);
  bucket_kernel<<<1, 256, 0, stream>>>(sel, perm, tiles);
  convert_x_kernel<<<(BZd * Td * Dd) / 1024, 256, 0, stream>>>(x, xbf);

  for (int c = 0; c < NC; c++) {
    transpose_bf16_kernel<<<dim3(Dd / 64, FC / 64, Ed), 256, 0, stream>>>(
        W1, w1t, 0, c * FC, DFFd, (size_t)Dd * DFFd, Dd, (size_t)FC * Dd);
    transpose_bf16_kernel<<<dim3(FC / 64, Dd / 64, Ed), 256, 0, stream>>>(
        W2, w2t, c * FC, 0, Dd, (size_t)DFFd * Dd, FC, (size_t)Dd * FC);
    gemm1_kernel<<<dim3(FC / 128, MAXTILES), 256, 0, stream>>>(
        xbf, w1t, b1, perm, tiles, h, c * FC, FC);
    gemm2_kernel<<<dim3(Dd / 128, MAXTILES), 256, 0, stream>>>(
        h, w2t, b2, perm, tiles, out, FC, c == 0 ? 1 : 0);
  }
}